// Round 7
// baseline (223.521 us; speedup 1.0000x reference)
//
#include <hip/hip_runtime.h>
#include <hip/hip_bf16.h>

typedef __bf16 bf16_t;
typedef __bf16 bf16x8 __attribute__((ext_vector_type(8)));
typedef float  f32x4  __attribute__((ext_vector_type(4)));

#define DM    512
#define NQKV  1536
#define NTOK  65536
#define TM    48          // tokens per block (3 x 16 m-frags)
#define QSTR  1544        // qkv LDS row stride (elems): 1536 + 8 pad

// Fragment-major repacked weights ("flatmm shuffle"): for wave w (0..7),
// K-step s (0..15), ni (0..11), lane l (0..63), elem e (0..7):
//   g_wt2[(((w*16+s)*12+ni)*64 + l)*8 + e] = W^T[n][k]
//   with n = w*192+ni*16+(l&15), k = s*32+(l>>4)*8+e.
__device__ __align__(16) bf16_t g_wt2[(size_t)NQKV * DM];

#define MEMFENCE asm volatile("" ::: "memory")

// ---------------------------------------------------------------------------
// Kernel 1: scatter W_q|W_k|W_v (fp32 [k][n]) -> g_wt2 fragment-major bf16
// ---------------------------------------------------------------------------
__global__ void prep_w2(const float* __restrict__ Wq,
                        const float* __restrict__ Wk,
                        const float* __restrict__ Wv) {
    int flat = blockIdx.x * 256 + threadIdx.x;   // 0..98303 (one bf16x8 each)
    int l  = flat & 63;
    int kg = l >> 4, lr = l & 15;
    int t2 = flat >> 6;
    int ni = t2 % 12;
    int t3 = t2 / 12;
    int s  = t3 & 15, w = t3 >> 4;
    int n  = w * 192 + ni * 16 + lr;             // 0..1535
    int k0 = s * 32 + kg * 8;
    int mat = n >> 9, nn = n & 511;
    const float* W = (mat == 0) ? Wq : ((mat == 1) ? Wk : Wv);
    bf16x8 v;
#pragma unroll
    for (int e = 0; e < 8; ++e) v[e] = (bf16_t)W[(k0 + e) * DM + nn];
    *(bf16x8*)(g_wt2 + (size_t)flat * 8) = v;
}

// ---------------------------------------------------------------------------
// Kernel 2: fused QKV projection + cross-head attention, flatmm-style.
// 48 tokens/block, 8 waves. A (x tile) in LDS; B streamed global->reg->MFMA
// (half-step pipelined, barrier-free K-loop); qkv stays in LDS.
// ---------------------------------------------------------------------------
__global__ __launch_bounds__(512, 1) void fused_mha(
    const float* __restrict__ x, float* __restrict__ out) {
    extern __shared__ char sm[];        // qkv [48][QSTR] bf16 = 148224 B
    // A tile [48][512] bf16 chunk-swizzled aliases sm[0..49152) (dead after K-loop)

    const int tid = threadIdx.x;
    const int l   = tid & 63, w = tid >> 6;
    const int lr  = l & 15,  kg = l >> 4;
    const size_t tok0 = (size_t)blockIdx.x * TM;
    const int ntb = (int)(((size_t)NTOK - tok0) < TM ? (NTOK - tok0) : TM);

    // ---- stage x tile: fp32 global -> bf16 LDS, 16B-chunk XOR swizzle ------
    {
        const int rbase = tid >> 5;               // 0..15
        const int cj    = tid & 31;               // chunk base
#pragma unroll
        for (int p = 0; p < 3; ++p) {
            int r = p * 16 + rbase;               // 0..47
            if (r < ntb) {
                const float* xp = x + (tok0 + r) * DM;
                int r7 = r & 7;
#pragma unroll
                for (int jj = 0; jj < 2; ++jj) {
                    int c = cj + jj * 32;         // chunk 0..63 (8 bf16 each)
                    float4 f0 = *(const float4*)(xp + c * 8);
                    float4 f1 = *(const float4*)(xp + c * 8 + 4);
                    bf16x8 v;
                    v[0] = (bf16_t)f0.x; v[1] = (bf16_t)f0.y;
                    v[2] = (bf16_t)f0.z; v[3] = (bf16_t)f0.w;
                    v[4] = (bf16_t)f1.x; v[5] = (bf16_t)f1.y;
                    v[6] = (bf16_t)f1.z; v[7] = (bf16_t)f1.w;
                    *(bf16x8*)(sm + r * 1024 + ((c ^ r7) << 4)) = v;
                }
            }
        }
    }

    // ---- B prefetch: step 0, two half-groups (ni 0..5 / 6..11) ------------
    const bf16_t* gw = g_wt2 + ((size_t)w * 16 * 12 * 64 + l) * 8;
    bf16x8 bx[6], by[6];
#pragma unroll
    for (int ni = 0; ni < 6; ++ni) bx[ni] = *(const bf16x8*)(gw + ni * 512);
#pragma unroll
    for (int ni = 0; ni < 6; ++ni) by[ni] = *(const bf16x8*)(gw + (6 + ni) * 512);

    // my ds_writes drained; B reg-loads stay in flight across the barrier
    asm volatile("s_waitcnt lgkmcnt(0)" ::: "memory");
    __builtin_amdgcn_s_barrier();
    MEMFENCE;

    // ---- barrier-free K-loop: 16 steps, 36 MFMA/step, half-step B pipeline -
    f32x4 acc[3][12];
#pragma unroll
    for (int a = 0; a < 3; ++a)
#pragma unroll
        for (int b = 0; b < 12; ++b) acc[a][b] = (f32x4){0.f, 0.f, 0.f, 0.f};

    const int sx = (lr & 7) << 4;               // A-read swizzle term

#pragma unroll
    for (int s = 0; s < 16; ++s) {
        bf16x8 af[3];
#pragma unroll
        for (int mi = 0; mi < 3; ++mi)
            af[mi] = *(const bf16x8*)(sm + (mi * 16 + lr) * 1024 +
                                      ((s * 64 + kg * 16) ^ sx));
        // half X: MFMA on bx(s), then refill bx <- step s+1
#pragma unroll
        for (int mi = 0; mi < 3; ++mi)
#pragma unroll
            for (int ni = 0; ni < 6; ++ni)
                acc[mi][ni] = __builtin_amdgcn_mfma_f32_16x16x32_bf16(
                    af[mi], bx[ni], acc[mi][ni], 0, 0, 0);
        if (s < 15) {
#pragma unroll
            for (int ni = 0; ni < 6; ++ni)
                bx[ni] = *(const bf16x8*)(gw + ((s + 1) * 12 + ni) * 512);
        }
        // half Y: MFMA on by(s), then refill by <- step s+1
#pragma unroll
        for (int mi = 0; mi < 3; ++mi)
#pragma unroll
            for (int ni = 0; ni < 6; ++ni)
                acc[mi][6 + ni] = __builtin_amdgcn_mfma_f32_16x16x32_bf16(
                    af[mi], by[ni], acc[mi][6 + ni], 0, 0, 0);
        if (s < 15) {
#pragma unroll
            for (int ni = 0; ni < 6; ++ni)
                by[ni] = *(const bf16x8*)(gw + ((s + 1) * 12 + 6 + ni) * 512);
        }
    }

    // ---- A region dead; sync before qkv overwrites it ----------------------
    asm volatile("s_waitcnt lgkmcnt(0)" ::: "memory");
    __builtin_amdgcn_s_barrier();
    MEMFENCE;

    // ---- epilogue: acc -> qkv LDS [48][QSTR] (row = token, col = n) --------
    bf16_t* qkv = (bf16_t*)sm;
#pragma unroll
    for (int mi = 0; mi < 3; ++mi)
#pragma unroll
        for (int ni = 0; ni < 12; ++ni) {
            int col = w * 192 + ni * 16 + lr;
#pragma unroll
            for (int i = 0; i < 4; ++i) {
                int token = mi * 16 + kg * 4 + i;
                qkv[token * QSTR + col] = (bf16_t)acc[mi][ni][i];
            }
        }
    asm volatile("s_waitcnt lgkmcnt(0)" ::: "memory");
    __builtin_amdgcn_s_barrier();
    MEMFENCE;

    // ---- attention: 16 threads/token, two passes (0..31, 32..47) ----------
#pragma unroll
    for (int p = 0; p < 2; ++p) {
        const int tok = p * 32 + (tid >> 4);
        if (tok < ntb) {
            const int tj = tid & 15, h = tj & 7, d0 = (tj >> 3) << 5;
            const bf16_t* base = qkv + tok * QSTR;

            float qv[32];
            {
                const bf16_t* qp = base + h * 64 + d0;
#pragma unroll
                for (int j = 0; j < 4; ++j) {
                    bf16x8 q8 = *(const bf16x8*)(qp + 8 * j);
#pragma unroll
                    for (int e = 0; e < 8; ++e) qv[8 * j + e] = (float)q8[e];
                }
            }

            float s[8];
#pragma unroll
            for (int t = 0; t < 8; ++t) {
                const bf16_t* kp = base + 512 + t * 64 + d0;
                float a = 0.f;
#pragma unroll
                for (int j = 0; j < 4; ++j) {
                    bf16x8 k8 = *(const bf16x8*)(kp + 8 * j);
#pragma unroll
                    for (int e = 0; e < 8; ++e) a += qv[8 * j + e] * (float)k8[e];
                }
                s[t] = a;
            }
            // combine two d-halves (partner lane tid^8: same tok, same h)
#pragma unroll
            for (int t = 0; t < 8; ++t) s[t] += __shfl_xor(s[t], 8, 64);

            float m = s[0];
#pragma unroll
            for (int t = 1; t < 8; ++t) m = fmaxf(m, s[t]);
            float pr[8], psum = 0.f;
#pragma unroll
            for (int t = 0; t < 8; ++t) {
                pr[t] = exp2f((s[t] - m) * 1.44269504088896f);
                psum += pr[t];
            }
            float inv = 1.0f / psum;

            float o[32];
#pragma unroll
            for (int e = 0; e < 32; ++e) o[e] = 0.f;
#pragma unroll
            for (int t = 0; t < 8; ++t) {
                float pt = pr[t] * inv;
                const bf16_t* vp = base + 1024 + t * 64 + d0;
#pragma unroll
                for (int j = 0; j < 4; ++j) {
                    bf16x8 v8 = *(const bf16x8*)(vp + 8 * j);
#pragma unroll
                    for (int e = 0; e < 8; ++e) o[8 * j + e] += pt * (float)v8[e];
                }
            }

            float* op = out + (tok0 + tok) * DM + h * 64 + d0;
#pragma unroll
            for (int j = 0; j < 8; ++j) {
                float4 o4 = {o[4 * j], o[4 * j + 1], o[4 * j + 2], o[4 * j + 3]};
                *(float4*)(op + 4 * j) = o4;
            }
        }
    }
}

// ---------------------------------------------------------------------------
extern "C" void kernel_launch(void* const* d_in, const int* in_sizes, int n_in,
                              void* d_out, int out_size, void* d_ws, size_t ws_size,
                              hipStream_t stream) {
    (void)d_ws; (void)ws_size; (void)n_in; (void)out_size;
    const float* x  = (const float*)d_in[0];
    const float* Wq = (const float*)d_in[1];
    const float* Wk = (const float*)d_in[2];
    const float* Wv = (const float*)d_in[3];
    float* out = (float*)d_out;

    int ntok = in_sizes[0] / DM;                   // 65536
    int grid = (ntok + TM - 1) / TM;               // 1366 (last block: 16 tokens)
    prep_w2<<<384, 256, 0, stream>>>(Wq, Wk, Wv);
    size_t lds = (size_t)TM * QSTR * sizeof(bf16_t);   // 148224 B
    fused_mha<<<grid, 512, lds, stream>>>(x, out);
}